// Round 2
// baseline (19908.183 us; speedup 1.0000x reference)
//
#include <hip/hip_runtime.h>
#include <hip/hip_cooperative_groups.h>

namespace cg = cooperative_groups;

typedef _Float16 v8h __attribute__((ext_vector_type(8)));
typedef float v4f __attribute__((ext_vector_type(4)));

#define MFMA16(a, b, c) __builtin_amdgcn_mfma_f32_16x16x32_f16((a), (b), (c), 0, 0, 0)

static constexpr int NHID = 1024;
static constexpr int NBAT = 128;
static constexpr int NST  = 512;
static constexpr size_t OUT_BSTRIDE = (size_t)NST * NHID;    // 524288
static constexpr size_t OUT_HF = (size_t)NBAT * NST * NHID;  // 67108864

// ws byte offsets
static constexpr size_t WS_WPK  = 0;         // merged fp16 hi weights: 8,388,608 B
static constexpr size_t WS_WLO  = 8388608;   // merged fp16 lo weights: 8,388,608 B
static constexpr size_t WS_WSEP = 16777216;  // separate 6-gate fp16 weights: 12,582,912 B
static constexpr size_t WS_BPK  = 29360128;  // packed biases: 4096 floats = 16,384 B
static constexpr size_t WS_X0F  = 29376512;  // x0 fp16 A-frag: 262,144 B
static constexpr size_t WS_HB0  = 29638656;  // h hi ping (also h0 hi): 262,144 B
static constexpr size_t WS_HB1  = 29900800;  // h hi pong: 262,144 B
static constexpr size_t WS_HL0  = 30162944;  // h lo ping (also h0 lo): 262,144 B
static constexpr size_t WS_HL1  = 30425088;  // h lo pong: 262,144 B

// ---------------- prep: pack weights/biases to fp16 fragment layouts ----------------
// unit sections (1 unit = 1 thread):
// S0 [0,524288): Wpk/Wlo merged  u = ((jg*4+gate)*32+kc)*64+lane, 8 halves each
// S1 [524288,1310720): Wsep      u = ((jg*6+g6)*32+kc)*64+lane
// S2 [1310720,1314816): bpk      u = (jg*4+gate)*16+n
// S3 [1314816,1347584): x0 -> out[:,0,:], float4 each
// S4 [1347584,1363968): x0 -> X0f fp16 A-frag
// S5 [1363968,1380352): h0 -> Hb0/Hl0 hi/lo A-frag
__global__ __launch_bounds__(256) void prep_kernel(
    const float* __restrict__ x0, const float* __restrict__ h0,
    const float* __restrict__ Wih, const float* __restrict__ Whh,
    const float* __restrict__ bih, const float* __restrict__ bhh,
    _Float16* __restrict__ Wpk, _Float16* __restrict__ Wlo,
    _Float16* __restrict__ Wsep,
    float* __restrict__ bpk, _Float16* __restrict__ X0f,
    _Float16* __restrict__ H0f, _Float16* __restrict__ H0l,
    float* __restrict__ out)
{
  int u = blockIdx.x * 256 + threadIdx.x;
  if (u < 524288) {  // merged weights: r,z = Wih+Whh ; in = Wih_n ; hn = Whh_n
    int lane = u & 63, kc = (u >> 6) & 31, gate = (u >> 11) & 3, jg = u >> 13;
    int n = lane & 15, q = lane >> 4;
    int k = kc * 32 + q * 8;
    int j = jg * 16 + n;
    const float *r0, *r1 = nullptr;
    if (gate == 0)      { r0 = Wih + (size_t)j * NHID + k;            r1 = Whh + (size_t)j * NHID + k; }
    else if (gate == 1) { r0 = Wih + (size_t)(NHID + j) * NHID + k;   r1 = Whh + (size_t)(NHID + j) * NHID + k; }
    else if (gate == 2) { r0 = Wih + (size_t)(2 * NHID + j) * NHID + k; }
    else                { r0 = Whh + (size_t)(2 * NHID + j) * NHID + k; }
    float4 a0 = *(const float4*)r0, a1 = *(const float4*)(r0 + 4);
    float v[8] = {a0.x, a0.y, a0.z, a0.w, a1.x, a1.y, a1.z, a1.w};
    if (r1) {
      float4 c0 = *(const float4*)r1, c1 = *(const float4*)(r1 + 4);
      v[0] += c0.x; v[1] += c0.y; v[2] += c0.z; v[3] += c0.w;
      v[4] += c1.x; v[5] += c1.y; v[6] += c1.z; v[7] += c1.w;
    }
    v8h oh, ol;
    for (int i = 0; i < 8; ++i) {
      _Float16 hh = (_Float16)v[i];
      oh[i] = hh;
      ol[i] = (_Float16)(v[i] - (float)hh);
    }
    *(v8h*)(Wpk + (size_t)u * 8) = oh;
    *(v8h*)(Wlo + (size_t)u * 8) = ol;
    return;
  }
  u -= 524288;
  if (u < 786432) {  // separate weights for step 1: g6 0..2 = Wih r/z/n, 3..5 = Whh r/z/n
    int lane = u & 63, kc = (u >> 6) & 31;
    int gg = u >> 11;
    int g6 = gg % 6, jg = gg / 6;
    int n = lane & 15, q = lane >> 4;
    int k = kc * 32 + q * 8;
    int j = jg * 16 + n;
    const float* r0 = (g6 < 3) ? (Wih + (size_t)(g6 * NHID + j) * NHID + k)
                               : (Whh + (size_t)((g6 - 3) * NHID + j) * NHID + k);
    float4 a0 = *(const float4*)r0, a1 = *(const float4*)(r0 + 4);
    float v[8] = {a0.x, a0.y, a0.z, a0.w, a1.x, a1.y, a1.z, a1.w};
    v8h o;
    for (int i = 0; i < 8; ++i) o[i] = (_Float16)v[i];
    *(v8h*)(Wsep + (size_t)u * 8) = o;
    return;
  }
  u -= 786432;
  if (u < 4096) {  // biases: r,z merged; in = bih_n; hn = bhh_n
    int n = u & 15, gate = (u >> 4) & 3, jg = u >> 6;
    int j = jg * 16 + n;
    float v;
    if (gate == 0)      v = bih[j] + bhh[j];
    else if (gate == 1) v = bih[NHID + j] + bhh[NHID + j];
    else if (gate == 2) v = bih[2 * NHID + j];
    else                v = bhh[2 * NHID + j];
    bpk[u] = v;
    return;
  }
  u -= 4096;
  if (u < 32768) {  // x0 -> out[:,0,:]
    int b = u >> 8;
    int j4 = (u & 255) * 4;
    *(float4*)(out + (size_t)b * OUT_BSTRIDE + j4) = *(const float4*)(x0 + (size_t)b * NHID + j4);
    return;
  }
  u -= 32768;
  if (u < 16384) {  // x0 -> fp16 A-frag (single precision fp16; step-1 only)
    int lane = u & 63, kc = (u >> 6) & 31, mt = u >> 11;
    int b = mt * 16 + (lane & 15);
    int k = kc * 32 + (lane >> 4) * 8;
    float4 a0 = *(const float4*)(x0 + (size_t)b * NHID + k);
    float4 a1 = *(const float4*)(x0 + (size_t)b * NHID + k + 4);
    v8h o;
    o[0]=(_Float16)a0.x; o[1]=(_Float16)a0.y; o[2]=(_Float16)a0.z; o[3]=(_Float16)a0.w;
    o[4]=(_Float16)a1.x; o[5]=(_Float16)a1.y; o[6]=(_Float16)a1.z; o[7]=(_Float16)a1.w;
    *(v8h*)(X0f + (size_t)u * 8) = o;
    return;
  }
  u -= 16384;
  if (u < 16384) {  // h0 -> hi/lo A-frags (into Hb0 / Hl0)
    int lane = u & 63, kc = (u >> 6) & 31, mt = u >> 11;
    int b = mt * 16 + (lane & 15);
    int k = kc * 32 + (lane >> 4) * 8;
    float4 a0 = *(const float4*)(h0 + (size_t)b * NHID + k);
    float4 a1 = *(const float4*)(h0 + (size_t)b * NHID + k + 4);
    float v[8] = {a0.x, a0.y, a0.z, a0.w, a1.x, a1.y, a1.z, a1.w};
    v8h oh, ol;
    for (int i = 0; i < 8; ++i) {
      _Float16 hh = (_Float16)v[i];
      oh[i] = hh;
      ol[i] = (_Float16)(v[i] - (float)hh);
    }
    *(v8h*)(H0f + (size_t)u * 8) = oh;
    *(v8h*)(H0l + (size_t)u * 8) = ol;
    return;
  }
}

// ---------------- persistent GRU kernel: steps 1..511, grid.sync between steps ----------------
// grid = 256 WGs (mt = bx>>6 in [0,4): 32 batch rows; jg = bx&63: 16 hidden cols, all 4 gates)
// block = 512 thr = 8 waves: wave w -> (mh = w&1: which 16 of the 32 rows, ks = w>>1: k-quarter)
__global__ __launch_bounds__(512, 2) void gru_persist(
    const float* __restrict__ h0,
    const _Float16* __restrict__ Wpk, const _Float16* __restrict__ Wlo,
    const _Float16* __restrict__ Wsep,
    const float* __restrict__ bpk, const _Float16* __restrict__ X0f,
    _Float16* __restrict__ Hb0, _Float16* __restrict__ Hb1,
    _Float16* __restrict__ Hl0, _Float16* __restrict__ Hl1,
    float* __restrict__ out)
{
  extern __shared__ char smem[];
  _Float16* WL = (_Float16*)smem;        // 131072 B: 4 gates x 32 kc x 1024 B (hi weights)
  float* Cb = (float*)(smem + 131072);   // 16384 B: 16 slots x 256 floats

  const int tid = threadIdx.x;
  const int bx = blockIdx.x;
  const int jg = bx & 63;
  const int mt = bx >> 6;
  const int w = tid >> 6;
  const int lane = tid & 63;
  const int mh = w & 1;
  const int ks = w >> 1;
  const int m16 = mt * 2 + mh;
  const int q = lane >> 4;
  const int cc = lane & 15;

  // stage merged hi weights to LDS (131072 B)
  {
    const v8h* src = (const v8h*)(Wpk + (size_t)jg * 65536);
    v8h* dst = (v8h*)WL;
    #pragma unroll
    for (int i = 0; i < 16; ++i) dst[tid + i * 512] = src[tid + i * 512];
  }

  const int j_l = tid & 15;
  const int b_l = tid >> 4;
  const int mhb = b_l >> 4;
  const int jglob = jg * 16 + j_l;
  const int bglob = mt * 32 + b_l;
  const float* bB = bpk + jg * 64;
  const float b_r = bB[j_l], b_z = bB[16 + j_l], b_i = bB[32 + j_l], b_h = bB[48 + j_l];
  float hprev = h0[(size_t)bglob * NHID + jglob];  // fp32 master copy, stays in a register
  float* outp = out + (size_t)bglob * OUT_BSTRIDE + jglob;

  __syncthreads();
  cg::grid_group grid = cg::this_grid();

  for (int t = 1; t < NST; ++t) {
    v4f acc[4];
    #pragma unroll
    for (int g = 0; g < 4; ++g) acc[g] = (v4f){0.f, 0.f, 0.f, 0.f};

    if (t == 1) {
      // x0 != h0: r/z from x*Wih + h*Whh ; in from x*Wih_n ; hn from h*Whh_n (weights from L2)
      const v8h* Xf  = (const v8h*)X0f + (size_t)m16 * 32 * 64;
      const v8h* Hf  = (const v8h*)Hb0 + (size_t)m16 * 32 * 64;
      const v8h* Hlf = (const v8h*)Hl0 + (size_t)m16 * 32 * 64;
      const v8h* Ws  = (const v8h*)Wsep + (size_t)jg * 6 * 32 * 64;
      #pragma unroll 2
      for (int kc = ks * 8; kc < ks * 8 + 8; ++kc) {
        v8h xa = Xf[kc * 64 + lane];
        v8h ha = Hf[kc * 64 + lane];
        v8h hl = Hlf[kc * 64 + lane];
        v8h w0 = Ws[(0 * 32 + kc) * 64 + lane];
        v8h w1 = Ws[(1 * 32 + kc) * 64 + lane];
        v8h w2 = Ws[(2 * 32 + kc) * 64 + lane];
        v8h w3 = Ws[(3 * 32 + kc) * 64 + lane];
        v8h w4 = Ws[(4 * 32 + kc) * 64 + lane];
        v8h w5 = Ws[(5 * 32 + kc) * 64 + lane];
        acc[0] = MFMA16(xa, w0, acc[0]);
        acc[1] = MFMA16(xa, w1, acc[1]);
        acc[2] = MFMA16(xa, w2, acc[2]);
        acc[0] = MFMA16(ha, w3, acc[0]);
        acc[1] = MFMA16(ha, w4, acc[1]);
        acc[3] = MFMA16(ha, w5, acc[3]);
        acc[0] = MFMA16(hl, w3, acc[0]);
        acc[1] = MFMA16(hl, w4, acc[1]);
        acc[3] = MFMA16(hl, w5, acc[3]);
      }
    } else {
      const _Float16* hin  = (t & 1) ? Hb0 : Hb1;  // hi plane of step t-1's output
      const _Float16* hinl = (t & 1) ? Hl0 : Hl1;  // lo plane
      const v8h* Af  = (const v8h*)hin  + (size_t)m16 * 32 * 64;
      const v8h* Al  = (const v8h*)hinl + (size_t)m16 * 32 * 64;
      const v8h* BL  = (const v8h*)WL;
      const v8h* Blo = (const v8h*)Wlo + (size_t)jg * 8192;
      #pragma unroll 2
      for (int kc = ks * 8; kc < ks * 8 + 8; ++kc) {
        v8h a  = Af[kc * 64 + lane];
        v8h al = Al[kc * 64 + lane];
        #pragma unroll
        for (int g = 0; g < 4; ++g) {
          v8h bh = BL[(g * 32 + kc) * 64 + lane];
          v8h bl = Blo[(g * 32 + kc) * 64 + lane];
          acc[g] = MFMA16(a,  bh, acc[g]);
          acc[g] = MFMA16(a,  bl, acc[g]);
          acc[g] = MFMA16(al, bh, acc[g]);
        }
      }
    }

    // ---- cross-wave k-reduction (4 k-quarters -> waves ks==0), log2 rounds in LDS ----
    if (ks >= 2) {
      const int slot = (w - 4) * 4;
      #pragma unroll
      for (int g = 0; g < 4; ++g)
        #pragma unroll
        for (int r = 0; r < 4; ++r)
          Cb[(slot + g) * 256 + (q * 4 + r) * 16 + cc] = acc[g][r];
    }
    __syncthreads();
    if (ks < 2) {
      const int slot = w * 4;
      #pragma unroll
      for (int g = 0; g < 4; ++g)
        #pragma unroll
        for (int r = 0; r < 4; ++r)
          acc[g][r] += Cb[(slot + g) * 256 + (q * 4 + r) * 16 + cc];
    }
    __syncthreads();
    if (ks == 1) {
      const int slot = (w - 2) * 4;
      #pragma unroll
      for (int g = 0; g < 4; ++g)
        #pragma unroll
        for (int r = 0; r < 4; ++r)
          Cb[(slot + g) * 256 + (q * 4 + r) * 16 + cc] = acc[g][r];
    }
    __syncthreads();
    if (w < 2) {  // ks==0: final accumulate + publish (slots mh*4+g)
      const int slot = w * 4;
      #pragma unroll
      for (int g = 0; g < 4; ++g)
        #pragma unroll
        for (int r = 0; r < 4; ++r)
          acc[g][r] += Cb[(slot + g) * 256 + (q * 4 + r) * 16 + cc];
      #pragma unroll
      for (int g = 0; g < 4; ++g)
        #pragma unroll
        for (int r = 0; r < 4; ++r)
          Cb[(slot + g) * 256 + (q * 4 + r) * 16 + cc] = acc[g][r];
    }
    __syncthreads();

    // ---- gate math: one thread per (b_l, j_l) output, fp32 ----
    const int rowi = (b_l & 15) * 16 + j_l;
    const float pr = Cb[(mhb * 4 + 0) * 256 + rowi] + b_r;
    const float pz = Cb[(mhb * 4 + 1) * 256 + rowi] + b_z;
    const float pi = Cb[(mhb * 4 + 2) * 256 + rowi] + b_i;
    const float ph = Cb[(mhb * 4 + 3) * 256 + rowi] + b_h;
    const float r = 1.f / (1.f + __expf(-pr));
    const float z = 1.f / (1.f + __expf(-pz));
    const float nv = pi + r * ph;
    const float n = 2.f / (1.f + __expf(-2.f * nv)) - 1.f;
    const float hnew = (1.f - z) * n + z * hprev;
    hprev = hnew;
    outp[(size_t)t * NHID] = hnew;
    if (t == NST - 1) out[OUT_HF + (size_t)bglob * NHID + jglob] = hnew;
    // fp16 hi/lo copies in A-fragment layout for next step's MFMA
    _Float16* ho  = (t & 1) ? Hb1 : Hb0;
    _Float16* hol = (t & 1) ? Hl1 : Hl0;
    const int laneo = (bglob & 15) | (((jglob >> 3) & 3) << 4);
    const size_t hidx = ((size_t)(bglob >> 4) * 32 + (jglob >> 5)) * 512 + (size_t)laneo * 8 + (jglob & 7);
    _Float16 hh = (_Float16)hnew;
    ho[hidx] = hh;
    hol[hidx] = (_Float16)(hnew - (float)hh);

    if (t < NST - 1) grid.sync();
  }
}

extern "C" void kernel_launch(void* const* d_in, const int* in_sizes, int n_in,
                              void* d_out, int out_size, void* d_ws, size_t ws_size,
                              hipStream_t stream) {
  const float* x0  = (const float*)d_in[0];
  const float* h0  = (const float*)d_in[1];
  const float* Wih = (const float*)d_in[3];
  const float* Whh = (const float*)d_in[4];
  const float* bih = (const float*)d_in[5];
  const float* bhh = (const float*)d_in[6];
  float* out = (float*)d_out;
  char* ws = (char*)d_ws;
  _Float16* Wpk  = (_Float16*)(ws + WS_WPK);
  _Float16* Wlo  = (_Float16*)(ws + WS_WLO);
  _Float16* Wsep = (_Float16*)(ws + WS_WSEP);
  float*    bpk  = (float*)(ws + WS_BPK);
  _Float16* X0f  = (_Float16*)(ws + WS_X0F);
  _Float16* Hb0  = (_Float16*)(ws + WS_HB0);
  _Float16* Hb1  = (_Float16*)(ws + WS_HB1);
  _Float16* Hl0  = (_Float16*)(ws + WS_HL0);
  _Float16* Hl1  = (_Float16*)(ws + WS_HL1);

  hipLaunchKernelGGL(prep_kernel, dim3(5392), dim3(256), 0, stream,
                     x0, h0, Wih, Whh, bih, bhh, Wpk, Wlo, Wsep, bpk, X0f, Hb0, Hl0, out);

  (void)hipFuncSetAttribute((const void*)gru_persist,
                            hipFuncAttributeMaxDynamicSharedMemorySize, 147456);
  void* args[] = {(void*)&h0, (void*)&Wpk, (void*)&Wlo, (void*)&Wsep, (void*)&bpk,
                  (void*)&X0f, (void*)&Hb0, (void*)&Hb1, (void*)&Hl0, (void*)&Hl1,
                  (void*)&out};
  (void)hipLaunchCooperativeKernel((void*)gru_persist, dim3(256), dim3(512),
                                   args, 147456, stream);
}

// Round 3
// 6592.876 us; speedup vs baseline: 3.0197x; 3.0197x over previous
//
#include <hip/hip_runtime.h>

typedef _Float16 v8h __attribute__((ext_vector_type(8)));
typedef float v4f __attribute__((ext_vector_type(4)));

#define MFMA16(a, b, c) __builtin_amdgcn_mfma_f32_16x16x32_f16((a), (b), (c), 0, 0, 0)

static constexpr int NHID = 1024;
static constexpr int NBAT = 128;
static constexpr int NST  = 512;
static constexpr size_t OUT_BSTRIDE = (size_t)NST * NHID;    // 524288
static constexpr size_t OUT_HF = (size_t)NBAT * NST * NHID;  // 67108864

// ws byte offsets
static constexpr size_t WS_WPK  = 0;         // merged fp16 hi weights: 8,388,608 B
static constexpr size_t WS_WLO  = 8388608;   // merged fp16 lo weights: 8,388,608 B
static constexpr size_t WS_WSEP = 16777216;  // separate 6-gate fp16 weights: 12,582,912 B
static constexpr size_t WS_BPK  = 29360128;  // packed biases: 4096 floats = 16,384 B
static constexpr size_t WS_X0F  = 29376512;  // x0 fp16 A-frag: 262,144 B
static constexpr size_t WS_HB0  = 29638656;  // h hi ping (also h0 hi): 262,144 B
static constexpr size_t WS_HB1  = 29900800;  // h hi pong: 262,144 B
static constexpr size_t WS_HL0  = 30162944;  // h lo ping (also h0 lo): 262,144 B
static constexpr size_t WS_HL1  = 30425088;  // h lo pong: 262,144 B
static constexpr size_t WS_SLOT = 30687232;  // barrier slots: 256 uints = 1,024 B

// agent-scope (sc1, MALL-coherent, L1/L2-bypassing) helpers
__device__ inline v8h load_h16_agent(const _Float16* p) {
  const unsigned long long* q = (const unsigned long long*)p;
  unsigned long long a = __hip_atomic_load(q,     __ATOMIC_RELAXED, __HIP_MEMORY_SCOPE_AGENT);
  unsigned long long b = __hip_atomic_load(q + 1, __ATOMIC_RELAXED, __HIP_MEMORY_SCOPE_AGENT);
  union { unsigned long long u[2]; v8h v; } cv;
  cv.u[0] = a; cv.u[1] = b;
  return cv.v;
}

// ---------------- prep: pack weights/biases to fp16 fragment layouts ----------------
__global__ __launch_bounds__(256) void prep_kernel(
    const float* __restrict__ x0, const float* __restrict__ h0,
    const float* __restrict__ Wih, const float* __restrict__ Whh,
    const float* __restrict__ bih, const float* __restrict__ bhh,
    _Float16* __restrict__ Wpk, _Float16* __restrict__ Wlo,
    _Float16* __restrict__ Wsep,
    float* __restrict__ bpk, _Float16* __restrict__ X0f,
    _Float16* __restrict__ H0f, _Float16* __restrict__ H0l,
    unsigned* __restrict__ slots,
    float* __restrict__ out)
{
  int u = blockIdx.x * 256 + threadIdx.x;
  if (u < 524288) {  // merged weights hi/lo: r,z = Wih+Whh ; in = Wih_n ; hn = Whh_n
    int lane = u & 63, kc = (u >> 6) & 31, gate = (u >> 11) & 3, jg = u >> 13;
    int n = lane & 15, q = lane >> 4;
    int k = kc * 32 + q * 8;
    int j = jg * 16 + n;
    const float *r0, *r1 = nullptr;
    if (gate == 0)      { r0 = Wih + (size_t)j * NHID + k;            r1 = Whh + (size_t)j * NHID + k; }
    else if (gate == 1) { r0 = Wih + (size_t)(NHID + j) * NHID + k;   r1 = Whh + (size_t)(NHID + j) * NHID + k; }
    else if (gate == 2) { r0 = Wih + (size_t)(2 * NHID + j) * NHID + k; }
    else                { r0 = Whh + (size_t)(2 * NHID + j) * NHID + k; }
    float4 a0 = *(const float4*)r0, a1 = *(const float4*)(r0 + 4);
    float v[8] = {a0.x, a0.y, a0.z, a0.w, a1.x, a1.y, a1.z, a1.w};
    if (r1) {
      float4 c0 = *(const float4*)r1, c1 = *(const float4*)(r1 + 4);
      v[0] += c0.x; v[1] += c0.y; v[2] += c0.z; v[3] += c0.w;
      v[4] += c1.x; v[5] += c1.y; v[6] += c1.z; v[7] += c1.w;
    }
    v8h oh, ol;
    for (int i = 0; i < 8; ++i) {
      _Float16 hh = (_Float16)v[i];
      oh[i] = hh;
      ol[i] = (_Float16)(v[i] - (float)hh);
    }
    *(v8h*)(Wpk + (size_t)u * 8) = oh;
    *(v8h*)(Wlo + (size_t)u * 8) = ol;
    return;
  }
  u -= 524288;
  if (u < 786432) {  // separate weights for step 1
    int lane = u & 63, kc = (u >> 6) & 31;
    int gg = u >> 11;
    int g6 = gg % 6, jg = gg / 6;
    int n = lane & 15, q = lane >> 4;
    int k = kc * 32 + q * 8;
    int j = jg * 16 + n;
    const float* r0 = (g6 < 3) ? (Wih + (size_t)(g6 * NHID + j) * NHID + k)
                               : (Whh + (size_t)((g6 - 3) * NHID + j) * NHID + k);
    float4 a0 = *(const float4*)r0, a1 = *(const float4*)(r0 + 4);
    float v[8] = {a0.x, a0.y, a0.z, a0.w, a1.x, a1.y, a1.z, a1.w};
    v8h o;
    for (int i = 0; i < 8; ++i) o[i] = (_Float16)v[i];
    *(v8h*)(Wsep + (size_t)u * 8) = o;
    return;
  }
  u -= 786432;
  if (u < 4096) {  // biases
    int n = u & 15, gate = (u >> 4) & 3, jg = u >> 6;
    int j = jg * 16 + n;
    float v;
    if (gate == 0)      v = bih[j] + bhh[j];
    else if (gate == 1) v = bih[NHID + j] + bhh[NHID + j];
    else if (gate == 2) v = bih[2 * NHID + j];
    else                v = bhh[2 * NHID + j];
    bpk[u] = v;
    return;
  }
  u -= 4096;
  if (u < 32768) {  // x0 -> out[:,0,:]
    int b = u >> 8;
    int j4 = (u & 255) * 4;
    *(float4*)(out + (size_t)b * OUT_BSTRIDE + j4) = *(const float4*)(x0 + (size_t)b * NHID + j4);
    return;
  }
  u -= 32768;
  if (u < 16384) {  // x0 -> fp16 A-frag
    int lane = u & 63, kc = (u >> 6) & 31, mt = u >> 11;
    int b = mt * 16 + (lane & 15);
    int k = kc * 32 + (lane >> 4) * 8;
    float4 a0 = *(const float4*)(x0 + (size_t)b * NHID + k);
    float4 a1 = *(const float4*)(x0 + (size_t)b * NHID + k + 4);
    v8h o;
    o[0]=(_Float16)a0.x; o[1]=(_Float16)a0.y; o[2]=(_Float16)a0.z; o[3]=(_Float16)a0.w;
    o[4]=(_Float16)a1.x; o[5]=(_Float16)a1.y; o[6]=(_Float16)a1.z; o[7]=(_Float16)a1.w;
    *(v8h*)(X0f + (size_t)u * 8) = o;
    return;
  }
  u -= 16384;
  if (u < 16384) {  // h0 -> hi/lo A-frags
    int lane = u & 63, kc = (u >> 6) & 31, mt = u >> 11;
    int b = mt * 16 + (lane & 15);
    int k = kc * 32 + (lane >> 4) * 8;
    float4 a0 = *(const float4*)(h0 + (size_t)b * NHID + k);
    float4 a1 = *(const float4*)(h0 + (size_t)b * NHID + k + 4);
    float v[8] = {a0.x, a0.y, a0.z, a0.w, a1.x, a1.y, a1.z, a1.w};
    v8h oh, ol;
    for (int i = 0; i < 8; ++i) {
      _Float16 hh = (_Float16)v[i];
      oh[i] = hh;
      ol[i] = (_Float16)(v[i] - (float)hh);
    }
    *(v8h*)(H0f + (size_t)u * 8) = oh;
    *(v8h*)(H0l + (size_t)u * 8) = ol;
    return;
  }
  u -= 16384;
  if (u < 256) {  // zero barrier slots
    slots[u] = 0;
    return;
  }
}

// ---------------- persistent GRU kernel: steps 1..511, custom fence-free barrier ----------------
// grid = 256 WGs (mt = bx>>6: 32 batch rows; jg = bx&63: 16 hidden cols x 4 gates)
// block = 512 thr = 8 waves: wave w -> (mh = w&1, ks = w>>1: k-quarter)
__global__ __launch_bounds__(512, 2) void gru_persist(
    const float* __restrict__ h0,
    const _Float16* __restrict__ Wpk, const _Float16* __restrict__ Wlo,
    const _Float16* __restrict__ Wsep,
    const float* __restrict__ bpk, const _Float16* __restrict__ X0f,
    _Float16* __restrict__ Hb0, _Float16* __restrict__ Hb1,
    _Float16* __restrict__ Hl0, _Float16* __restrict__ Hl1,
    unsigned* __restrict__ slots,
    float* __restrict__ out)
{
  extern __shared__ char smem[];
  _Float16* WL = (_Float16*)smem;             // 131072 B: hi weights, 4 gates x 32 kc
  float* Cb = (float*)(smem + 131072);        // 20480 B: 16 slots x 16 rows x stride 20
  _Float16* SH = (_Float16*)(smem + 151552);  // 2048 B: h staging [m16h][plane][256]

  const int tid = threadIdx.x;
  const int bx = blockIdx.x;
  const int jg = bx & 63;
  const int mt = bx >> 6;
  const int w = tid >> 6;
  const int lane = tid & 63;
  const int mh = w & 1;
  const int ks = w >> 1;
  const int m16 = mt * 2 + mh;
  const int q = lane >> 4;
  const int cc = lane & 15;

  // stage merged hi weights to LDS (131072 B)
  {
    const v8h* src = (const v8h*)(Wpk + (size_t)jg * 65536);
    v8h* dst = (v8h*)WL;
    #pragma unroll
    for (int i = 0; i < 16; ++i) dst[tid + i * 512] = src[tid + i * 512];
  }

  const int j_l = tid & 15;
  const int b_l = tid >> 4;
  const int mhb = b_l >> 4;
  const int jglob = jg * 16 + j_l;
  const int bglob = mt * 32 + b_l;
  const float* bB = bpk + jg * 64;
  const float b_r = bB[j_l], b_z = bB[16 + j_l], b_i = bB[32 + j_l], b_h = bB[48 + j_l];
  float hprev = h0[(size_t)bglob * NHID + jglob];  // fp32 master copy in a register
  float* outp = out + (size_t)bglob * OUT_BSTRIDE + jglob;

  __syncthreads();

  for (int t = 1; t < NST; ++t) {
    v4f accf[4];

    if (t == 1) {
      v4f acc[4];
      #pragma unroll
      for (int g = 0; g < 4; ++g) acc[g] = (v4f){0.f, 0.f, 0.f, 0.f};
      const v8h* Xf  = (const v8h*)X0f + (size_t)m16 * 32 * 64;
      const v8h* Hf  = (const v8h*)Hb0 + (size_t)m16 * 32 * 64;
      const v8h* Hlf = (const v8h*)Hl0 + (size_t)m16 * 32 * 64;
      const v8h* Ws  = (const v8h*)Wsep + (size_t)jg * 6 * 32 * 64;
      #pragma unroll 2
      for (int kc = ks * 8; kc < ks * 8 + 8; ++kc) {
        v8h xa = Xf[kc * 64 + lane];
        v8h ha = Hf[kc * 64 + lane];
        v8h hl = Hlf[kc * 64 + lane];
        acc[0] = MFMA16(xa, Ws[(0 * 32 + kc) * 64 + lane], acc[0]);
        acc[1] = MFMA16(xa, Ws[(1 * 32 + kc) * 64 + lane], acc[1]);
        acc[2] = MFMA16(xa, Ws[(2 * 32 + kc) * 64 + lane], acc[2]);
        v8h w3 = Ws[(3 * 32 + kc) * 64 + lane];
        v8h w4 = Ws[(4 * 32 + kc) * 64 + lane];
        v8h w5 = Ws[(5 * 32 + kc) * 64 + lane];
        acc[0] = MFMA16(ha, w3, acc[0]);
        acc[1] = MFMA16(ha, w4, acc[1]);
        acc[3] = MFMA16(ha, w5, acc[3]);
        acc[0] = MFMA16(hl, w3, acc[0]);
        acc[1] = MFMA16(hl, w4, acc[1]);
        acc[3] = MFMA16(hl, w5, acc[3]);
      }
      #pragma unroll
      for (int g = 0; g < 4; ++g) accf[g] = acc[g];
    } else {
      const _Float16* hinH = (t & 1) ? Hb0 : Hb1;
      const _Float16* hinL = (t & 1) ? Hl0 : Hl1;
      const _Float16* AfH = hinH + (size_t)m16 * 16384;
      const _Float16* AfL = hinL + (size_t)m16 * 16384;
      const v8h* BL  = (const v8h*)WL;
      const v8h* Blo = (const v8h*)Wlo + (size_t)jg * 8192;
      v4f acc[4][2];
      #pragma unroll
      for (int g = 0; g < 4; ++g) { acc[g][0] = (v4f){0.f,0.f,0.f,0.f}; acc[g][1] = (v4f){0.f,0.f,0.f,0.f}; }
      #pragma unroll 2
      for (int kk = 0; kk < 8; ++kk) {
        const int kc = ks * 8 + kk;
        v8h a  = load_h16_agent(AfH + (size_t)(kc * 64 + lane) * 8);
        v8h al = load_h16_agent(AfL + (size_t)(kc * 64 + lane) * 8);
        const int par = kk & 1;
        #pragma unroll
        for (int g = 0; g < 4; ++g) {
          v8h bh = BL[(g * 32 + kc) * 64 + lane];
          v8h bl = Blo[(g * 32 + kc) * 64 + lane];
          acc[g][par] = MFMA16(a,  bh, acc[g][par]);
          acc[g][par] = MFMA16(a,  bl, acc[g][par]);
          acc[g][par] = MFMA16(al, bh, acc[g][par]);
        }
      }
      #pragma unroll
      for (int g = 0; g < 4; ++g) accf[g] = acc[g][0] + acc[g][1];
    }

    // ---- cross-wave k-reduction (stride-20 padded: 2-way max bank aliasing) ----
    if (ks >= 2) {
      const int slot = (w - 4) * 4;
      #pragma unroll
      for (int g = 0; g < 4; ++g)
        #pragma unroll
        for (int r = 0; r < 4; ++r)
          Cb[(slot + g) * 320 + (q * 4 + r) * 20 + cc] = accf[g][r];
    }
    __syncthreads();
    if (ks < 2) {
      const int slot = w * 4;
      #pragma unroll
      for (int g = 0; g < 4; ++g)
        #pragma unroll
        for (int r = 0; r < 4; ++r)
          accf[g][r] += Cb[(slot + g) * 320 + (q * 4 + r) * 20 + cc];
    }
    __syncthreads();
    if (ks == 1) {
      const int slot = (w - 2) * 4;
      #pragma unroll
      for (int g = 0; g < 4; ++g)
        #pragma unroll
        for (int r = 0; r < 4; ++r)
          Cb[(slot + g) * 320 + (q * 4 + r) * 20 + cc] = accf[g][r];
    }
    __syncthreads();
    if (w < 2) {
      const int slot = w * 4;
      #pragma unroll
      for (int g = 0; g < 4; ++g)
        #pragma unroll
        for (int r = 0; r < 4; ++r)
          accf[g][r] += Cb[(slot + g) * 320 + (q * 4 + r) * 20 + cc];
      #pragma unroll
      for (int g = 0; g < 4; ++g)
        #pragma unroll
        for (int r = 0; r < 4; ++r)
          Cb[(slot + g) * 320 + (q * 4 + r) * 20 + cc] = accf[g][r];
    }
    __syncthreads();

    // ---- gate math: one thread per (b_l, j_l) output, fp32 ----
    const float pr = Cb[(mhb * 4 + 0) * 320 + (b_l & 15) * 20 + j_l] + b_r;
    const float pz = Cb[(mhb * 4 + 1) * 320 + (b_l & 15) * 20 + j_l] + b_z;
    const float pi = Cb[(mhb * 4 + 2) * 320 + (b_l & 15) * 20 + j_l] + b_i;
    const float ph = Cb[(mhb * 4 + 3) * 320 + (b_l & 15) * 20 + j_l] + b_h;
    const float r = 1.f / (1.f + __expf(-pr));
    const float z = 1.f / (1.f + __expf(-pz));
    const float nv = pi + r * ph;
    const float n = 2.f / (1.f + __expf(-2.f * nv)) - 1.f;
    const float hnew = (1.f - z) * n + z * hprev;
    hprev = hnew;
    outp[(size_t)t * NHID] = hnew;

    if (t == NST - 1) {
      out[OUT_HF + (size_t)bglob * NHID + jglob] = hnew;
      break;
    }

    // ---- stage next-step h (hi/lo A-frag layout) into LDS ----
    {
      const int reg = (b_l >> 4) * 2;
      const int idx = (b_l & 15) * 8 + (j_l >> 3) * 128 + (j_l & 7);
      _Float16 hh = (_Float16)hnew;
      SH[reg * 256 + idx] = hh;
      SH[(reg + 1) * 256 + idx] = (_Float16)(hnew - (float)hh);
    }
    __syncthreads();

    // ---- coalesced agent-scope (sc1) copy LDS -> global h buffers ----
    {
      _Float16* hoH = (t & 1) ? Hb1 : Hb0;
      _Float16* hoL = (t & 1) ? Hl1 : Hl0;
      const int rg = tid >> 7;          // 0..3 : [m16h][plane]
      const int d  = tid & 127;
      const int m16o = mt * 2 + (rg >> 1);
      _Float16* plane = (rg & 1) ? hoL : hoH;
      unsigned* dst = (unsigned*)plane + ((m16o * 32 + (jg >> 1)) * 256 + (jg & 1) * 128 + d);
      unsigned val = *(const unsigned*)(SH + (rg * 256 + d * 2));
      __hip_atomic_store(dst, val, __ATOMIC_RELAXED, __HIP_MEMORY_SCOPE_AGENT);
    }
    asm volatile("s_waitcnt vmcnt(0)" ::: "memory");
    __syncthreads();

    // ---- decentralized fence-free barrier ----
    if (tid == 0)
      __hip_atomic_store(slots + bx, (unsigned)t, __ATOMIC_RELAXED, __HIP_MEMORY_SCOPE_AGENT);
    if (w == 0) {
      const unsigned long long* sp = (const unsigned long long*)slots;
      const unsigned tt = (unsigned)t;
      for (;;) {
        unsigned long long a = __hip_atomic_load(sp + lane * 2,     __ATOMIC_RELAXED, __HIP_MEMORY_SCOPE_AGENT);
        unsigned long long b = __hip_atomic_load(sp + lane * 2 + 1, __ATOMIC_RELAXED, __HIP_MEMORY_SCOPE_AGENT);
        bool ok = ((unsigned)a >= tt) && ((unsigned)(a >> 32) >= tt) &&
                  ((unsigned)b >= tt) && ((unsigned)(b >> 32) >= tt);
        if (__all(ok)) break;
      }
    }
    __syncthreads();
    asm volatile("" ::: "memory");
  }
}

extern "C" void kernel_launch(void* const* d_in, const int* in_sizes, int n_in,
                              void* d_out, int out_size, void* d_ws, size_t ws_size,
                              hipStream_t stream) {
  const float* x0  = (const float*)d_in[0];
  const float* h0  = (const float*)d_in[1];
  const float* Wih = (const float*)d_in[3];
  const float* Whh = (const float*)d_in[4];
  const float* bih = (const float*)d_in[5];
  const float* bhh = (const float*)d_in[6];
  float* out = (float*)d_out;
  char* ws = (char*)d_ws;
  _Float16* Wpk  = (_Float16*)(ws + WS_WPK);
  _Float16* Wlo  = (_Float16*)(ws + WS_WLO);
  _Float16* Wsep = (_Float16*)(ws + WS_WSEP);
  float*    bpk  = (float*)(ws + WS_BPK);
  _Float16* X0f  = (_Float16*)(ws + WS_X0F);
  _Float16* Hb0  = (_Float16*)(ws + WS_HB0);
  _Float16* Hb1  = (_Float16*)(ws + WS_HB1);
  _Float16* Hl0  = (_Float16*)(ws + WS_HL0);
  _Float16* Hl1  = (_Float16*)(ws + WS_HL1);
  unsigned* slots = (unsigned*)(ws + WS_SLOT);

  hipLaunchKernelGGL(prep_kernel, dim3(5393), dim3(256), 0, stream,
                     x0, h0, Wih, Whh, bih, bhh, Wpk, Wlo, Wsep, bpk, X0f, Hb0, Hl0,
                     slots, out);

  (void)hipFuncSetAttribute((const void*)gru_persist,
                            hipFuncAttributeMaxDynamicSharedMemorySize, 153600);
  void* args[] = {(void*)&h0, (void*)&Wpk, (void*)&Wlo, (void*)&Wsep, (void*)&bpk,
                  (void*)&X0f, (void*)&Hb0, (void*)&Hb1, (void*)&Hl0, (void*)&Hl1,
                  (void*)&slots, (void*)&out};
  (void)hipLaunchCooperativeKernel((void*)gru_persist, dim3(256), dim3(512),
                                   args, 153600, stream);
}

// Round 4
// 5554.964 us; speedup vs baseline: 3.5839x; 1.1868x over previous
//
#include <hip/hip_runtime.h>

typedef _Float16 v8h __attribute__((ext_vector_type(8)));
typedef float v4f __attribute__((ext_vector_type(4)));

#define MFMA16(a, b, c) __builtin_amdgcn_mfma_f32_16x16x32_f16((a), (b), (c), 0, 0, 0)

static constexpr int NHID = 1024;
static constexpr int NBAT = 128;
static constexpr int NST  = 512;
static constexpr size_t OUT_BSTRIDE = (size_t)NST * NHID;    // 524288
static constexpr size_t OUT_HF = (size_t)NBAT * NST * NHID;  // 67108864

// ws byte offsets
static constexpr size_t WS_WPK  = 0;         // merged fp16 hi weights: 8,388,608 B
static constexpr size_t WS_WLO  = 8388608;   // merged fp16 lo weights: 8,388,608 B
static constexpr size_t WS_WSEP = 16777216;  // separate 6-gate fp16 weights: 12,582,912 B
static constexpr size_t WS_BPK  = 29360128;  // packed biases: 4096 floats = 16,384 B
static constexpr size_t WS_X0F  = 29376512;  // x0 fp16 A-frag: 262,144 B
static constexpr size_t WS_HB0  = 29638656;  // h hi ping (also h0 hi): 262,144 B
static constexpr size_t WS_HB1  = 29900800;  // h hi pong: 262,144 B
static constexpr size_t WS_HL0  = 30162944;  // h lo ping (also h0 lo): 262,144 B
static constexpr size_t WS_HL1  = 30425088;  // h lo pong: 262,144 B
static constexpr size_t WS_SLOT = 30687232;  // barrier slots: 256 uints = 1,024 B

// agent-scope (sc1, MALL-coherent, L1/L2-bypassing) helpers
__device__ inline v8h load_h16_agent(const _Float16* p) {
  const unsigned long long* q = (const unsigned long long*)p;
  unsigned long long a = __hip_atomic_load(q,     __ATOMIC_RELAXED, __HIP_MEMORY_SCOPE_AGENT);
  unsigned long long b = __hip_atomic_load(q + 1, __ATOMIC_RELAXED, __HIP_MEMORY_SCOPE_AGENT);
  union { unsigned long long u[2]; v8h v; } cv;
  cv.u[0] = a; cv.u[1] = b;
  return cv.v;
}

// ---------------- prep: pack weights/biases to fp16 fragment layouts ----------------
__global__ __launch_bounds__(256) void prep_kernel(
    const float* __restrict__ x0, const float* __restrict__ h0,
    const float* __restrict__ Wih, const float* __restrict__ Whh,
    const float* __restrict__ bih, const float* __restrict__ bhh,
    _Float16* __restrict__ Wpk, _Float16* __restrict__ Wlo,
    _Float16* __restrict__ Wsep,
    float* __restrict__ bpk, _Float16* __restrict__ X0f,
    _Float16* __restrict__ H0f, _Float16* __restrict__ H0l,
    unsigned* __restrict__ slots,
    float* __restrict__ out)
{
  int u = blockIdx.x * 256 + threadIdx.x;
  if (u < 524288) {  // merged weights hi/lo: r,z = Wih+Whh ; in = Wih_n ; hn = Whh_n
    int lane = u & 63, kc = (u >> 6) & 31, gate = (u >> 11) & 3, jg = u >> 13;
    int n = lane & 15, q = lane >> 4;
    int k = kc * 32 + q * 8;
    int j = jg * 16 + n;
    const float *r0, *r1 = nullptr;
    if (gate == 0)      { r0 = Wih + (size_t)j * NHID + k;            r1 = Whh + (size_t)j * NHID + k; }
    else if (gate == 1) { r0 = Wih + (size_t)(NHID + j) * NHID + k;   r1 = Whh + (size_t)(NHID + j) * NHID + k; }
    else if (gate == 2) { r0 = Wih + (size_t)(2 * NHID + j) * NHID + k; }
    else                { r0 = Whh + (size_t)(2 * NHID + j) * NHID + k; }
    float4 a0 = *(const float4*)r0, a1 = *(const float4*)(r0 + 4);
    float v[8] = {a0.x, a0.y, a0.z, a0.w, a1.x, a1.y, a1.z, a1.w};
    if (r1) {
      float4 c0 = *(const float4*)r1, c1 = *(const float4*)(r1 + 4);
      v[0] += c0.x; v[1] += c0.y; v[2] += c0.z; v[3] += c0.w;
      v[4] += c1.x; v[5] += c1.y; v[6] += c1.z; v[7] += c1.w;
    }
    v8h oh, ol;
    for (int i = 0; i < 8; ++i) {
      _Float16 hh = (_Float16)v[i];
      oh[i] = hh;
      ol[i] = (_Float16)(v[i] - (float)hh);
    }
    *(v8h*)(Wpk + (size_t)u * 8) = oh;
    *(v8h*)(Wlo + (size_t)u * 8) = ol;
    return;
  }
  u -= 524288;
  if (u < 786432) {  // separate weights for step 1
    int lane = u & 63, kc = (u >> 6) & 31;
    int gg = u >> 11;
    int g6 = gg % 6, jg = gg / 6;
    int n = lane & 15, q = lane >> 4;
    int k = kc * 32 + q * 8;
    int j = jg * 16 + n;
    const float* r0 = (g6 < 3) ? (Wih + (size_t)(g6 * NHID + j) * NHID + k)
                               : (Whh + (size_t)((g6 - 3) * NHID + j) * NHID + k);
    float4 a0 = *(const float4*)r0, a1 = *(const float4*)(r0 + 4);
    float v[8] = {a0.x, a0.y, a0.z, a0.w, a1.x, a1.y, a1.z, a1.w};
    v8h o;
    for (int i = 0; i < 8; ++i) o[i] = (_Float16)v[i];
    *(v8h*)(Wsep + (size_t)u * 8) = o;
    return;
  }
  u -= 786432;
  if (u < 4096) {  // biases
    int n = u & 15, gate = (u >> 4) & 3, jg = u >> 6;
    int j = jg * 16 + n;
    float v;
    if (gate == 0)      v = bih[j] + bhh[j];
    else if (gate == 1) v = bih[NHID + j] + bhh[NHID + j];
    else if (gate == 2) v = bih[2 * NHID + j];
    else                v = bhh[2 * NHID + j];
    bpk[u] = v;
    return;
  }
  u -= 4096;
  if (u < 32768) {  // x0 -> out[:,0,:]
    int b = u >> 8;
    int j4 = (u & 255) * 4;
    *(float4*)(out + (size_t)b * OUT_BSTRIDE + j4) = *(const float4*)(x0 + (size_t)b * NHID + j4);
    return;
  }
  u -= 32768;
  if (u < 16384) {  // x0 -> fp16 A-frag
    int lane = u & 63, kc = (u >> 6) & 31, mt = u >> 11;
    int b = mt * 16 + (lane & 15);
    int k = kc * 32 + (lane >> 4) * 8;
    float4 a0 = *(const float4*)(x0 + (size_t)b * NHID + k);
    float4 a1 = *(const float4*)(x0 + (size_t)b * NHID + k + 4);
    v8h o;
    o[0]=(_Float16)a0.x; o[1]=(_Float16)a0.y; o[2]=(_Float16)a0.z; o[3]=(_Float16)a0.w;
    o[4]=(_Float16)a1.x; o[5]=(_Float16)a1.y; o[6]=(_Float16)a1.z; o[7]=(_Float16)a1.w;
    *(v8h*)(X0f + (size_t)u * 8) = o;
    return;
  }
  u -= 16384;
  if (u < 16384) {  // h0 -> hi/lo A-frags
    int lane = u & 63, kc = (u >> 6) & 31, mt = u >> 11;
    int b = mt * 16 + (lane & 15);
    int k = kc * 32 + (lane >> 4) * 8;
    float4 a0 = *(const float4*)(h0 + (size_t)b * NHID + k);
    float4 a1 = *(const float4*)(h0 + (size_t)b * NHID + k + 4);
    float v[8] = {a0.x, a0.y, a0.z, a0.w, a1.x, a1.y, a1.z, a1.w};
    v8h oh, ol;
    for (int i = 0; i < 8; ++i) {
      _Float16 hh = (_Float16)v[i];
      oh[i] = hh;
      ol[i] = (_Float16)(v[i] - (float)hh);
    }
    *(v8h*)(H0f + (size_t)u * 8) = oh;
    *(v8h*)(H0l + (size_t)u * 8) = ol;
    return;
  }
  u -= 16384;
  if (u < 256) {  // zero barrier slots
    slots[u] = 0;
    return;
  }
}

// ---------------- persistent GRU kernel: steps 1..511, custom fence-free barrier ----------------
// grid = 256 WGs. XCD-aware remap: jg = (bx&7)*8 + ((bx>>3)&7), mt = bx>>6 — the 4 WGs
// sharing a jg (same Wlo slice) land on the same XCD (bx%8 round-robin) -> Wlo/XCD = 1 MB, L2-resident.
// block = 512 thr = 8 waves: wave w -> (mh = w&1, ks = w>>1: k-quarter)
__global__ __launch_bounds__(512, 2) void gru_persist(
    const float* __restrict__ h0,
    const _Float16* __restrict__ Wpk, const _Float16* __restrict__ Wlo,
    const _Float16* __restrict__ Wsep,
    const float* __restrict__ bpk, const _Float16* __restrict__ X0f,
    _Float16* __restrict__ Hb0, _Float16* __restrict__ Hb1,
    _Float16* __restrict__ Hl0, _Float16* __restrict__ Hl1,
    unsigned* __restrict__ slots,
    float* __restrict__ out)
{
  extern __shared__ char smem[];
  _Float16* WL = (_Float16*)smem;             // 131072 B: hi weights, 4 gates x 32 kc
  float* Cb = (float*)(smem + 131072);        // 30720 B: 24 slots x 16 rows x stride 20
  _Float16* SH = (_Float16*)(smem + 141312);  // 2048 B: aliases Cb slots 8..9 (dead after gather)

  const int tid = threadIdx.x;
  const int bx = blockIdx.x;
  const int jg = (bx & 7) * 8 + ((bx >> 3) & 7);  // XCD-aware remap
  const int mt = bx >> 6;
  const int w = tid >> 6;
  const int lane = tid & 63;
  const int mh = w & 1;
  const int ks = w >> 1;
  const int m16 = mt * 2 + mh;
  const int q = lane >> 4;
  const int cc = lane & 15;

  // stage merged hi weights to LDS (131072 B)
  {
    const v8h* src = (const v8h*)(Wpk + (size_t)jg * 65536);
    v8h* dst = (v8h*)WL;
    #pragma unroll
    for (int i = 0; i < 16; ++i) dst[tid + i * 512] = src[tid + i * 512];
  }

  const int j_l = tid & 15;
  const int b_l = tid >> 4;
  const int mhb = b_l >> 4;
  const int jglob = jg * 16 + j_l;
  const int bglob = mt * 32 + b_l;
  const float* bB = bpk + jg * 64;
  const float b_r = bB[j_l], b_z = bB[16 + j_l], b_i = bB[32 + j_l], b_h = bB[48 + j_l];
  float hprev = h0[(size_t)bglob * NHID + jglob];  // fp32 master copy in a register
  float* outp = out + (size_t)bglob * OUT_BSTRIDE + jglob;

  __syncthreads();

  for (int t = 1; t < NST; ++t) {
    v4f accf[4];

    if (t == 1) {
      v4f acc[4];
      #pragma unroll
      for (int g = 0; g < 4; ++g) acc[g] = (v4f){0.f, 0.f, 0.f, 0.f};
      const v8h* Xf  = (const v8h*)X0f + (size_t)m16 * 32 * 64;
      const v8h* Hf  = (const v8h*)Hb0 + (size_t)m16 * 32 * 64;
      const v8h* Hlf = (const v8h*)Hl0 + (size_t)m16 * 32 * 64;
      const v8h* Ws  = (const v8h*)Wsep + (size_t)jg * 6 * 32 * 64;
      #pragma unroll 2
      for (int kc = ks * 8; kc < ks * 8 + 8; ++kc) {
        v8h xa = Xf[kc * 64 + lane];
        v8h ha = Hf[kc * 64 + lane];
        v8h hl = Hlf[kc * 64 + lane];
        acc[0] = MFMA16(xa, Ws[(0 * 32 + kc) * 64 + lane], acc[0]);
        acc[1] = MFMA16(xa, Ws[(1 * 32 + kc) * 64 + lane], acc[1]);
        acc[2] = MFMA16(xa, Ws[(2 * 32 + kc) * 64 + lane], acc[2]);
        v8h w3 = Ws[(3 * 32 + kc) * 64 + lane];
        v8h w4 = Ws[(4 * 32 + kc) * 64 + lane];
        v8h w5 = Ws[(5 * 32 + kc) * 64 + lane];
        acc[0] = MFMA16(ha, w3, acc[0]);
        acc[1] = MFMA16(ha, w4, acc[1]);
        acc[3] = MFMA16(ha, w5, acc[3]);
        acc[0] = MFMA16(hl, w3, acc[0]);
        acc[1] = MFMA16(hl, w4, acc[1]);
        acc[3] = MFMA16(hl, w5, acc[3]);
      }
      #pragma unroll
      for (int g = 0; g < 4; ++g) accf[g] = acc[g];
    } else {
      const _Float16* hinH = (t & 1) ? Hb0 : Hb1;
      const _Float16* hinL = (t & 1) ? Hl0 : Hl1;
      const _Float16* AfH = hinH + (size_t)m16 * 16384;
      const _Float16* AfL = hinL + (size_t)m16 * 16384;
      const v8h* BL   = (const v8h*)WL;
      const v8h* BloP = (const v8h*)Wlo + (size_t)jg * 8192;
      v4f acc[4];
      #pragma unroll
      for (int g = 0; g < 4; ++g) acc[g] = (v4f){0.f, 0.f, 0.f, 0.f};
      const int kc0 = ks * 8;
      // software pipeline: prefetch h (MALL) and Blo (L2) one kc ahead
      v8h aH = load_h16_agent(AfH + (size_t)(kc0 * 64 + lane) * 8);
      v8h aL = load_h16_agent(AfL + (size_t)(kc0 * 64 + lane) * 8);
      v8h bl0 = BloP[(0 * 32 + kc0) * 64 + lane];
      v8h bl1 = BloP[(1 * 32 + kc0) * 64 + lane];
      v8h bl2 = BloP[(2 * 32 + kc0) * 64 + lane];
      v8h bl3 = BloP[(3 * 32 + kc0) * 64 + lane];
      #pragma unroll 2
      for (int kk = 0; kk < 8; ++kk) {
        const int kc = kc0 + kk;
        v8h caH = aH, caL = aL;
        v8h cb0 = bl0, cb1 = bl1, cb2 = bl2, cb3 = bl3;
        if (kk < 7) {
          aH = load_h16_agent(AfH + (size_t)((kc + 1) * 64 + lane) * 8);
          aL = load_h16_agent(AfL + (size_t)((kc + 1) * 64 + lane) * 8);
          bl0 = BloP[(0 * 32 + kc + 1) * 64 + lane];
          bl1 = BloP[(1 * 32 + kc + 1) * 64 + lane];
          bl2 = BloP[(2 * 32 + kc + 1) * 64 + lane];
          bl3 = BloP[(3 * 32 + kc + 1) * 64 + lane];
        }
        v8h bh0 = BL[(0 * 32 + kc) * 64 + lane];
        v8h bh1 = BL[(1 * 32 + kc) * 64 + lane];
        v8h bh2 = BL[(2 * 32 + kc) * 64 + lane];
        v8h bh3 = BL[(3 * 32 + kc) * 64 + lane];
        acc[0] = MFMA16(caH, bh0, acc[0]);
        acc[1] = MFMA16(caH, bh1, acc[1]);
        acc[2] = MFMA16(caH, bh2, acc[2]);
        acc[3] = MFMA16(caH, bh3, acc[3]);
        acc[0] = MFMA16(caH, cb0, acc[0]);
        acc[1] = MFMA16(caH, cb1, acc[1]);
        acc[2] = MFMA16(caH, cb2, acc[2]);
        acc[3] = MFMA16(caH, cb3, acc[3]);
        acc[0] = MFMA16(caL, bh0, acc[0]);
        acc[1] = MFMA16(caL, bh1, acc[1]);
        acc[2] = MFMA16(caL, bh2, acc[2]);
        acc[3] = MFMA16(caL, bh3, acc[3]);
      }
      #pragma unroll
      for (int g = 0; g < 4; ++g) accf[g] = acc[g];
    }

    // ---- cross-wave k-reduction: single-shot (2 syncthreads), stride-20 (2-way = free) ----
    if (ks >= 1) {
      const int base = (ks - 1) * 8 + mh * 4;
      #pragma unroll
      for (int g = 0; g < 4; ++g)
        #pragma unroll
        for (int r = 0; r < 4; ++r)
          Cb[(base + g) * 320 + (q * 4 + r) * 20 + cc] = accf[g][r];
    }
    __syncthreads();
    if (ks == 0) {
      const int b1 = mh * 4, b2 = 8 + mh * 4, b3 = 16 + mh * 4;
      #pragma unroll
      for (int g = 0; g < 4; ++g)
        #pragma unroll
        for (int r = 0; r < 4; ++r) {
          const int off = (q * 4 + r) * 20 + cc;
          float s = accf[g][r] + Cb[(b1 + g) * 320 + off]
                               + Cb[(b2 + g) * 320 + off]
                               + Cb[(b3 + g) * 320 + off];
          Cb[(b1 + g) * 320 + off] = s;  // publish final in slots 0..7
        }
    }
    __syncthreads();

    // ---- gate math: one thread per (b_l, j_l) output, fp32 ----
    const float pr = Cb[(mhb * 4 + 0) * 320 + (b_l & 15) * 20 + j_l] + b_r;
    const float pz = Cb[(mhb * 4 + 1) * 320 + (b_l & 15) * 20 + j_l] + b_z;
    const float pi = Cb[(mhb * 4 + 2) * 320 + (b_l & 15) * 20 + j_l] + b_i;
    const float ph = Cb[(mhb * 4 + 3) * 320 + (b_l & 15) * 20 + j_l] + b_h;
    const float r = 1.f / (1.f + __expf(-pr));
    const float z = 1.f / (1.f + __expf(-pz));
    const float nv = pi + r * ph;
    const float n = 2.f / (1.f + __expf(-2.f * nv)) - 1.f;
    const float hnew = (1.f - z) * n + z * hprev;
    hprev = hnew;

    if (t == NST - 1) {
      __builtin_nontemporal_store(hnew, outp + (size_t)t * NHID);
      __builtin_nontemporal_store(hnew, out + OUT_HF + (size_t)bglob * NHID + jglob);
      break;
    }

    // ---- stage next-step h (hi/lo A-frag layout) into LDS (aliases dead Cb slots) ----
    {
      const int reg = (b_l >> 4) * 2;
      const int idx = (b_l & 15) * 8 + (j_l >> 3) * 128 + (j_l & 7);
      _Float16 hh = (_Float16)hnew;
      SH[reg * 256 + idx] = hh;
      SH[(reg + 1) * 256 + idx] = (_Float16)(hnew - (float)hh);
    }
    __syncthreads();

    // ---- coalesced agent-scope (sc1) copy LDS -> global h buffers ----
    {
      _Float16* hoH = (t & 1) ? Hb1 : Hb0;
      _Float16* hoL = (t & 1) ? Hl1 : Hl0;
      const int rg = tid >> 7;          // 0..3 : [m16h][plane]
      const int d  = tid & 127;
      const int m16o = mt * 2 + (rg >> 1);
      _Float16* plane = (rg & 1) ? hoL : hoH;
      unsigned* dst = (unsigned*)plane + ((m16o * 32 + (jg >> 1)) * 256 + (jg & 1) * 128 + d);
      unsigned val = *(const unsigned*)(SH + (rg * 256 + d * 2));
      __hip_atomic_store(dst, val, __ATOMIC_RELAXED, __HIP_MEMORY_SCOPE_AGENT);
    }
    asm volatile("s_waitcnt vmcnt(0)" ::: "memory");

    // ---- arrival + xs store (xs latency hides under the poll) ----
    if (tid == 0)
      __hip_atomic_store(slots + bx, (unsigned)t, __ATOMIC_RELAXED, __HIP_MEMORY_SCOPE_AGENT);
    __builtin_nontemporal_store(hnew, outp + (size_t)t * NHID);

    // ---- decentralized fence-free barrier ----
    if (w == 0) {
      const unsigned long long* sp = (const unsigned long long*)slots;
      const unsigned tt = (unsigned)t;
      for (;;) {
        unsigned long long a = __hip_atomic_load(sp + lane * 2,     __ATOMIC_RELAXED, __HIP_MEMORY_SCOPE_AGENT);
        unsigned long long b = __hip_atomic_load(sp + lane * 2 + 1, __ATOMIC_RELAXED, __HIP_MEMORY_SCOPE_AGENT);
        bool ok = ((unsigned)a >= tt) && ((unsigned)(a >> 32) >= tt) &&
                  ((unsigned)b >= tt) && ((unsigned)(b >> 32) >= tt);
        if (__all(ok)) break;
      }
    }
    __syncthreads();
    asm volatile("" ::: "memory");
  }
}

extern "C" void kernel_launch(void* const* d_in, const int* in_sizes, int n_in,
                              void* d_out, int out_size, void* d_ws, size_t ws_size,
                              hipStream_t stream) {
  const float* x0  = (const float*)d_in[0];
  const float* h0  = (const float*)d_in[1];
  const float* Wih = (const float*)d_in[3];
  const float* Whh = (const float*)d_in[4];
  const float* bih = (const float*)d_in[5];
  const float* bhh = (const float*)d_in[6];
  float* out = (float*)d_out;
  char* ws = (char*)d_ws;
  _Float16* Wpk  = (_Float16*)(ws + WS_WPK);
  _Float16* Wlo  = (_Float16*)(ws + WS_WLO);
  _Float16* Wsep = (_Float16*)(ws + WS_WSEP);
  float*    bpk  = (float*)(ws + WS_BPK);
  _Float16* X0f  = (_Float16*)(ws + WS_X0F);
  _Float16* Hb0  = (_Float16*)(ws + WS_HB0);
  _Float16* Hb1  = (_Float16*)(ws + WS_HB1);
  _Float16* Hl0  = (_Float16*)(ws + WS_HL0);
  _Float16* Hl1  = (_Float16*)(ws + WS_HL1);
  unsigned* slots = (unsigned*)(ws + WS_SLOT);

  hipLaunchKernelGGL(prep_kernel, dim3(5393), dim3(256), 0, stream,
                     x0, h0, Wih, Whh, bih, bhh, Wpk, Wlo, Wsep, bpk, X0f, Hb0, Hl0,
                     slots, out);

  (void)hipFuncSetAttribute((const void*)gru_persist,
                            hipFuncAttributeMaxDynamicSharedMemorySize, 161792);
  void* args[] = {(void*)&h0, (void*)&Wpk, (void*)&Wlo, (void*)&Wsep, (void*)&bpk,
                  (void*)&X0f, (void*)&Hb0, (void*)&Hb1, (void*)&Hl0, (void*)&Hl1,
                  (void*)&slots, (void*)&out};
  (void)hipLaunchCooperativeKernel((void*)gru_persist, dim3(256), dim3(512),
                                   args, 161792, stream);
}